// Round 5
// baseline (291.711 us; speedup 1.0000x reference)
//
#include <hip/hip_runtime.h>

// RbfNet on MI355X — round 25 (spill fix):
// R24 counters: layer0_gemm WRITE_SIZE 274MB (expected 35MB), VGPR_Count=32,
// dur 77us -> the forced-residency asm batches collided with the
// launch_bounds(...,8) 64-VGPR cap and the allocator SPILLED the batch
// arrays to scratch (scratch = global mem -> 240MB of spill write traffic).
// Fix: launch_bounds(1024,4) / (256,4) -> 128-VGPR budget; batches (32 slots
// + decode + MFMA tail fragments ~= 90-100 VGPRs) become truly resident.
// Occupancy 8->4 waves/SIMD, but outstanding loads/SIMD goes ~8 -> 64-128.
// Everything else identical to R24: asm gather batches (16/32x
// global_load_dword saddr, tied "+v", waitcnt inside), records via
// s_load_dwordx4 -> SALU decode, uniform m branch.
// Record (4B): off=j*9+p (19b) | real-bit (1b) | wq (12b); w0 = wq*2^-12
// mantissa trick; pads (v=0) decode to w0=w1=0.

#define CAP 48

typedef __attribute__((ext_vector_type(8))) short short8;
typedef __attribute__((ext_vector_type(4))) short short4v;
typedef __attribute__((ext_vector_type(4))) float f32x4;
typedef int v4i __attribute__((ext_vector_type(4)));

__device__ __forceinline__ short bf16s(float f) {   // fp32 -> bf16 RNE
  unsigned u = __float_as_uint(f);
  return (short)((u + 0x7FFF + ((u >> 16) & 1)) >> 16);
}
__device__ __forceinline__ float b2f(unsigned short s) {
  return __uint_as_float(((unsigned)s) << 16);
}
__device__ __forceinline__ unsigned pack2(float a, float b) {
  return (unsigned)(unsigned short)bf16s(a) | ((unsigned)(unsigned short)bf16s(b) << 16);
}
__device__ __forceinline__ float dec_w0(int v) {    // w0 = wq * 2^-12, pad -> 0
  return __uint_as_float(0x3F800000u | (((unsigned)v & 0xFFFu) << 11)) - 1.0f;
}
__device__ __forceinline__ float dec_sf(int v) {    // 1.0 real record, 0.0 pad
  return (float)(((unsigned)v >> 12) & 1u);
}
// wave-uniform pointer -> SGPR pair (compiler can't prove uniformity of
// threadIdx-derived row pointers; readfirstlane makes it known-uniform)
__device__ __forceinline__ unsigned long long rfl64(unsigned long long x) {
  unsigned lo = __builtin_amdgcn_readfirstlane((unsigned)x);
  unsigned hi = __builtin_amdgcn_readfirstlane((unsigned)(x >> 32));
  return ((unsigned long long)hi << 32) | (unsigned long long)lo;
}

// ---- scalar record fetch: 32 records + cnt, all in SGPRs, wait inside asm ----
#define LOAD_RECS32(JROW, CPTR, RC, MRAW)                                   \
  {                                                                         \
    v4i s0_, s1_, s2_, s3_, s4_, s5_, s6_, s7_;                             \
    asm volatile(                                                           \
        "s_load_dwordx4 %0, %9, 0x0\n\t"                                    \
        "s_load_dwordx4 %1, %9, 0x10\n\t"                                   \
        "s_load_dwordx4 %2, %9, 0x20\n\t"                                   \
        "s_load_dwordx4 %3, %9, 0x30\n\t"                                   \
        "s_load_dwordx4 %4, %9, 0x40\n\t"                                   \
        "s_load_dwordx4 %5, %9, 0x50\n\t"                                   \
        "s_load_dwordx4 %6, %9, 0x60\n\t"                                   \
        "s_load_dwordx4 %7, %9, 0x70\n\t"                                   \
        "s_load_dword %8, %10, 0x0\n\t"                                     \
        "s_waitcnt lgkmcnt(0)"                                              \
        : "=&s"(s0_), "=&s"(s1_), "=&s"(s2_), "=&s"(s3_),                   \
          "=&s"(s4_), "=&s"(s5_), "=&s"(s6_), "=&s"(s7_), "=&s"(MRAW)       \
        : "s"(JROW), "s"(CPTR)                                              \
        : "memory");                                                        \
    _Pragma("unroll") for (int z_ = 0; z_ < 4; ++z_) {                      \
      RC[z_] = s0_[z_];      RC[4 + z_] = s1_[z_];                          \
      RC[8 + z_] = s2_[z_];  RC[12 + z_] = s3_[z_];                         \
      RC[16 + z_] = s4_[z_]; RC[20 + z_] = s5_[z_];                         \
      RC[24 + z_] = s6_[z_]; RC[28 + z_] = s7_[z_];                         \
    }                                                                       \
  }

#define LOAD_RECS16T(JROW, RT)                                              \
  {                                                                         \
    v4i t0_, t1_, t2_, t3_;                                                 \
    asm volatile(                                                           \
        "s_load_dwordx4 %0, %4, 0x80\n\t"                                   \
        "s_load_dwordx4 %1, %4, 0x90\n\t"                                   \
        "s_load_dwordx4 %2, %4, 0xA0\n\t"                                   \
        "s_load_dwordx4 %3, %4, 0xB0\n\t"                                   \
        "s_waitcnt lgkmcnt(0)"                                              \
        : "=&s"(t0_), "=&s"(t1_), "=&s"(t2_), "=&s"(t3_)                    \
        : "s"(JROW)                                                         \
        : "memory");                                                        \
    _Pragma("unroll") for (int z_ = 0; z_ < 4; ++z_) {                      \
      RT[z_] = t0_[z_];      RT[4 + z_] = t1_[z_];                          \
      RT[8 + z_] = t2_[z_];  RT[12 + z_] = t3_[z_];                         \
    }                                                                       \
  }

// ---- forced-residency gather batches: voff in, data out (tied regs), wait inside
#define GLDI(x) "global_load_dword %" #x ", %" #x ", %[bb]\n\t"

#define GATHER8(R, BASE)                                                    \
  asm volatile(                                                             \
      GLDI(0) GLDI(1) GLDI(2) GLDI(3) GLDI(4) GLDI(5) GLDI(6) GLDI(7)       \
      "s_waitcnt vmcnt(0)"                                                  \
      : "+v"(R[0]), "+v"(R[1]), "+v"(R[2]), "+v"(R[3]), "+v"(R[4]),         \
        "+v"(R[5]), "+v"(R[6]), "+v"(R[7])                                  \
      : [bb] "s"(BASE)                                                      \
      : "memory")

#define GATHER16(R, BASE)                                                   \
  asm volatile(                                                             \
      GLDI(0) GLDI(1) GLDI(2) GLDI(3) GLDI(4) GLDI(5) GLDI(6) GLDI(7)       \
      GLDI(8) GLDI(9) GLDI(10) GLDI(11) GLDI(12) GLDI(13) GLDI(14) GLDI(15) \
      "s_waitcnt vmcnt(0)"                                                  \
      : "+v"(R[0]), "+v"(R[1]), "+v"(R[2]), "+v"(R[3]), "+v"(R[4]),         \
        "+v"(R[5]), "+v"(R[6]), "+v"(R[7]), "+v"(R[8]), "+v"(R[9]),         \
        "+v"(R[10]), "+v"(R[11]), "+v"(R[12]), "+v"(R[13]), "+v"(R[14]),    \
        "+v"(R[15])                                                         \
      : [bb] "s"(BASE)                                                      \
      : "memory")

#define GATHER32(R, BASE)                                                   \
  asm volatile(                                                             \
      GLDI(0) GLDI(1) GLDI(2) GLDI(3) GLDI(4) GLDI(5) GLDI(6) GLDI(7)       \
      GLDI(8) GLDI(9) GLDI(10) GLDI(11) GLDI(12) GLDI(13) GLDI(14) GLDI(15) \
      GLDI(16) GLDI(17) GLDI(18) GLDI(19) GLDI(20) GLDI(21) GLDI(22)        \
      GLDI(23) GLDI(24) GLDI(25) GLDI(26) GLDI(27) GLDI(28) GLDI(29)        \
      GLDI(30) GLDI(31)                                                     \
      "s_waitcnt vmcnt(0)"                                                  \
      : "+v"(R[0]), "+v"(R[1]), "+v"(R[2]), "+v"(R[3]), "+v"(R[4]),         \
        "+v"(R[5]), "+v"(R[6]), "+v"(R[7]), "+v"(R[8]), "+v"(R[9]),         \
        "+v"(R[10]), "+v"(R[11]), "+v"(R[12]), "+v"(R[13]), "+v"(R[14]),    \
        "+v"(R[15]), "+v"(R[16]), "+v"(R[17]), "+v"(R[18]), "+v"(R[19]),    \
        "+v"(R[20]), "+v"(R[21]), "+v"(R[22]), "+v"(R[23]), "+v"(R[24]),    \
        "+v"(R[25]), "+v"(R[26]), "+v"(R[27]), "+v"(R[28]), "+v"(R[29]),    \
        "+v"(R[30]), "+v"(R[31])                                            \
      : [bb] "s"(BASE)                                                      \
      : "memory")

// ---------- fused: edge-bucket build | WTul prep | U0L0 prep (3 block ranges) ----------
__global__ void fill_prep(const float* __restrict__ dist,
                          const int* __restrict__ fi, const int* __restrict__ fj,
                          int* __restrict__ cnt, int* __restrict__ jw, int nE,
                          const float* __restrict__ cW1, const float* __restrict__ fW1,
                          const float* __restrict__ cW2, const float* __restrict__ fW2,
                          short* __restrict__ wt1, short* __restrict__ wt2,
                          const float* __restrict__ X,    // [n,4]
                          const float* __restrict__ cW0,  // [8,4,32]
                          const float* __restrict__ fW0,  // [4,32]
                          unsigned short* __restrict__ U0, int n,
                          int fillBlocks, int prepBlocks) {
  if ((int)blockIdx.x < fillBlocks) {
    int e = blockIdx.x * blockDim.x + threadIdx.x;
    if (e >= nE) return;
    int i = fi[e], j = fj[e];
    if (i == j) return;                  // centerIgnore
    float d = fminf(1.0f, fmaxf(-1.0f, dist[e]));
    float u = (d + 1.0f) * 3.5f;         // hat centers: spacing 2/7
    int p = min((int)u, 6);
    float w0 = 1.0f - (u - (float)p);
    int wq = min((int)(w0 * 4096.0f + 0.5f), 4095);
    unsigned off = (unsigned)(j * 9 + p);          // fused table offset
    int pos = atomicAdd(&cnt[i], 1);
    if (pos < CAP)
      jw[(size_t)i * CAP + pos] = (int)((off << 13) | 0x1000u | (unsigned)wq);
  } else if ((int)blockIdx.x < fillBlocks + prepBlocks) {
    int idx = ((int)blockIdx.x - fillBlocks) * blockDim.x + threadIdx.x;
    if (idx >= 2 * 576 * 64) return;
    int sel = idx / (576 * 64);
    int r = idx - sel * (576 * 64);
    int col = r >> 6, ch = r & 63;
    const float* cW = sel ? cW2 : cW1;
    const float* fW = sel ? fW2 : fW1;
    float v;
    if (col < 512) {
      int p = col >> 6, co = col & 63;
      v = cW[((size_t)p * 64 + ch) * 64 + co];
    } else {
      v = fW[(size_t)ch * 64 + (col - 512)];
    }
    (sel ? wt2 : wt1)[(size_t)col * 64 + ch] = bf16s(v);
  } else {
    // U0L0: [n,288] bf16, 4 channels/thread (groups of 4 never cross a p boundary)
    int idx = ((int)blockIdx.x - fillBlocks - prepBlocks) * blockDim.x + threadIdx.x;
    if (idx >= n * 72) return;
    int i = idx / 72, g = idx - i * 72;
    float4 x = *(const float4*)(X + (size_t)i * 4);
    float xk[4] = {x.x, x.y, x.z, x.w};
    float s[4] = {0, 0, 0, 0};
    if (g < 64) {                        // conv: p = g>>3, channels (g*4)&31 ..+3
      int p = g >> 3;
      int co = (g * 4) & 31;
      #pragma unroll
      for (int k = 0; k < 4; ++k) {
        const float* wr = cW0 + ((size_t)p * 4 + k) * 32 + co;
        #pragma unroll
        for (int c = 0; c < 4; ++c) s[c] = fmaf(xk[k], wr[c], s[c]);
      }
    } else {                             // lin: channels (g-64)*4 ..+3
      int co = (g - 64) * 4;
      #pragma unroll
      for (int k = 0; k < 4; ++k) {
        const float* wr = fW0 + (size_t)k * 32 + co;
        #pragma unroll
        for (int c = 0; c < 4; ++c) s[c] = fmaf(xk[k], wr[c], s[c]);
      }
    }
    uint2 pk = make_uint2(pack2(s[0], s[1]), pack2(s[2], s[3]));
    *(uint2*)(U0 + (size_t)i * 288 + g * 4) = pk;
  }
}

// ---- shared MFMA tail: UL[16,576] = sXa[16,64] @ WT^T; wave w does tiles w,w+16,(w+32)
__device__ __forceinline__ void gemm_tail(const unsigned short* sXa, short* sUL,
                                          const short* __restrict__ WT,
                                          int w, int lane) {
  const int mrow = lane & 15;
  const int quad = lane >> 4;
  short8 b0 = *(const short8*)(sXa + mrow * 64 + quad * 8);
  short8 b1 = *(const short8*)(sXa + mrow * 64 + quad * 8 + 32);
  const short* A0 = WT + (size_t)(w * 16 + mrow) * 64 + quad * 8;
  const short* A1 = WT + (size_t)((w + 16) * 16 + mrow) * 64 + quad * 8;
  short8 a00 = *(const short8*)(A0);
  short8 a01 = *(const short8*)(A0 + 32);
  short8 a10 = *(const short8*)(A1);
  short8 a11 = *(const short8*)(A1 + 32);
  const bool has3 = (w < 4);            // tiles 32..35 (36 total)
  short8 a20 = {0, 0, 0, 0, 0, 0, 0, 0};
  short8 a21 = {0, 0, 0, 0, 0, 0, 0, 0};
  if (has3) {
    const short* A2 = WT + (size_t)((w + 32) * 16 + mrow) * 64 + quad * 8;
    a20 = *(const short8*)(A2);
    a21 = *(const short8*)(A2 + 32);
  }
  __builtin_amdgcn_sched_barrier(0);    // all fragment loads in flight first
  f32x4 acc0 = {0, 0, 0, 0}, acc1 = {0, 0, 0, 0};
  acc0 = __builtin_amdgcn_mfma_f32_16x16x32_bf16(a00, b0, acc0, 0, 0, 0);
  acc0 = __builtin_amdgcn_mfma_f32_16x16x32_bf16(a01, b1, acc0, 0, 0, 0);
  acc1 = __builtin_amdgcn_mfma_f32_16x16x32_bf16(a10, b0, acc1, 0, 0, 0);
  acc1 = __builtin_amdgcn_mfma_f32_16x16x32_bf16(a11, b1, acc1, 0, 0, 0);
  short4v pk;
  #pragma unroll
  for (int r = 0; r < 4; ++r) pk[r] = bf16s(acc0[r]);
  *(short4v*)(sUL + mrow * 584 + w * 16 + quad * 4) = pk;
  #pragma unroll
  for (int r = 0; r < 4; ++r) pk[r] = bf16s(acc1[r]);
  *(short4v*)(sUL + mrow * 584 + (w + 16) * 16 + quad * 4) = pk;
  if (has3) {
    f32x4 acc2 = {0, 0, 0, 0};
    acc2 = __builtin_amdgcn_mfma_f32_16x16x32_bf16(a20, b0, acc2, 0, 0, 0);
    acc2 = __builtin_amdgcn_mfma_f32_16x16x32_bf16(a21, b1, acc2, 0, 0, 0);
    #pragma unroll
    for (int r = 0; r < 4; ++r) pk[r] = bf16s(acc2[r]);
    *(short4v*)(sUL + mrow * 584 + (w + 32) * 16 + quad * 4) = pk;
  }
}

// ---------- FUSED layer0 + gemm_ul1: 1024 threads, wave-per-node, no atomics ----------
__global__ __launch_bounds__(1024, 4) void layer0_gemm(
    const unsigned short* __restrict__ U0,  // [n,288] bf16 (p-major conv ++ lin)
    const int* __restrict__ cnt, const int* __restrict__ jw,
    const float* __restrict__ cb0, const float* __restrict__ fb0,
    const short* __restrict__ WTul,   // [576,64] bf16 layer-1 weights (L2-resident)
    unsigned short* __restrict__ UL, int n) {
  __shared__ __align__(16) unsigned short sXa[16 * 64];   // ansc0 tile, bf16
  __shared__ __align__(16) short sUL[16 * 584];           // UL staging
  const int tid = threadIdx.x;
  const int w = tid >> 6;                 // wave 0..15, owns node w
  const int lane = tid & 63;
  const int grp = lane >> 5;              // 0: even edges, 1: odd edges
  const int gl = lane & 31;               // uint index within the 64B slice pair
  const unsigned gl4 = (unsigned)gl * 4u;
  const int nodeBase = blockIdx.x * 16;
  const int i = nodeBase + w;
  const bool valid = (i < n);
  const int ic = valid ? i : 0;
  const int* jrow = (const int*)rfl64((unsigned long long)(jw + (size_t)ic * CAP));
  const int* cptr = (const int*)rfl64((unsigned long long)(cnt + ic));

  int rc[32]; int mraw;
  LOAD_RECS32(jrow, cptr, rc, mraw);
  const int m = valid ? min(mraw, CAP) : 0;
  float accLo = 0.0f, accHi = 0.0f;
  unsigned r[16];
  int vsel[16];
#define L0_FMA1(K)                                                          \
  {                                                                         \
    float w0_ = dec_w0(vsel[K]);                                            \
    float wgt_ = (gl < 16) ? w0_ : (dec_sf(vsel[K]) - w0_);                 \
    accLo = fmaf(wgt_, __uint_as_float(r[K] << 16), accLo);                 \
    accHi = fmaf(wgt_, __uint_as_float(r[K] & 0xFFFF0000u), accHi);         \
  }
  if (m > 0) {
    if (m <= 16) {                        // 8 slots cover 16 edges (pads = weight 0)
      #pragma unroll
      for (int k = 0; k < 8; ++k) {
        vsel[k] = grp ? rc[2 * k + 1] : rc[2 * k];
        r[k] = ((((unsigned)vsel[k]) >> 7) & 0xFFFFFFC0u) + gl4;
      }
      GATHER8(r, U0);
      #pragma unroll
      for (int k = 0; k < 8; ++k) L0_FMA1(k);
    } else {
      #pragma unroll
      for (int k = 0; k < 16; ++k) {
        vsel[k] = grp ? rc[2 * k + 1] : rc[2 * k];
        r[k] = ((((unsigned)vsel[k]) >> 7) & 0xFFFFFFC0u) + gl4;
      }
      GATHER16(r, U0);
      #pragma unroll
      for (int k = 0; k < 16; ++k) L0_FMA1(k);
      if (m > 32) {                       // edges 32..47 (P ~ 1e-4)
        int rt[16];
        LOAD_RECS16T(jrow, rt);
        #pragma unroll
        for (int k = 0; k < 8; ++k) {
          vsel[k] = grp ? rt[2 * k + 1] : rt[2 * k];
          r[k] = ((((unsigned)vsel[k]) >> 7) & 0xFFFFFFC0u) + gl4;
        }
        GATHER8(r, U0);
        #pragma unroll
        for (int k = 0; k < 8; ++k) L0_FMA1(k);
      }
    }
  }
#undef L0_FMA1
  accLo += __shfl_xor(accLo, 16, 64);     // merge u0/u1 roles
  accHi += __shfl_xor(accHi, 16, 64);
  accLo += __shfl_xor(accLo, 32, 64);     // merge even/odd edge groups
  accHi += __shfl_xor(accHi, 32, 64);
  if (lane < 16) {                        // lane l holds conv ch-pair (2l, 2l+1)
    const int l = lane;
    float c0v = fmaxf(accLo + cb0[2 * l], 0.0f);
    float c1v = fmaxf(accHi + cb0[2 * l + 1], 0.0f);
    unsigned lr = ((const unsigned*)(U0 + (size_t)ic * 288 + 256))[l];
    float l0 = fmaxf(__uint_as_float(lr << 16) + fb0[2 * l], 0.0f);
    float l1 = fmaxf(__uint_as_float(lr & 0xFFFF0000u) + fb0[2 * l + 1], 0.0f);
    unsigned* row = (unsigned*)(sXa + w * 64);
    row[l] = pack2(l0, l1);
    row[16 + l] = pack2(c0v, c1v);
  }
  __syncthreads();

  gemm_tail(sXa, sUL, WTul, w, lane);
  __syncthreads();
  const int r2 = tid >> 6;
  const int c0 = tid & 63;
  if (nodeBase + r2 < n) {
    unsigned short* dst = UL + (size_t)(nodeBase + r2) * 576;
    #pragma unroll
    for (int chunk = c0; chunk < 72; chunk += 64)
      *(short8*)(dst + chunk * 8) = *(const short8*)(sUL + r2 * 584 + chunk * 8);
  }
}

// ---------- FUSED conv1 + gemm_ul2: 1024 threads, 16 waves = 16 nodes ----------
__global__ __launch_bounds__(1024, 4) void conv_gemm(
    const unsigned short* __restrict__ ULA, // [n,576] bf16 (layer-1 U/L)
    const int* __restrict__ cnt, const int* __restrict__ jw,
    const float* __restrict__ cb, const float* __restrict__ fb,
    const short* __restrict__ WTul2,        // [576,64] bf16 layer-2 weights
    float* __restrict__ outAns,             // ans1 fp32 [n,64] (resid for conv2)
    unsigned short* __restrict__ ULB, int n) {
  __shared__ __align__(16) unsigned short sXa[16 * 64];   // ansc1 tile, bf16
  __shared__ __align__(16) short sUL[16 * 584];           // UL2 staging
  const int tid = threadIdx.x;
  const int w = tid >> 6;
  const int lane = tid & 63;
  const int half = lane >> 5;               // 0 -> u0 (w0), 1 -> u1 (w1)
  const int pl = lane & 31;
  const unsigned lane4 = (unsigned)lane * 4u;
  const int nodeBase = blockIdx.x * 16;
  const int i = nodeBase + w;
  const bool valid = (i < n);
  const int ic = valid ? i : 0;
  const int* jrow = (const int*)rfl64((unsigned long long)(jw + (size_t)ic * CAP));
  const int* cptr = (const int*)rfl64((unsigned long long)(cnt + ic));

  int rc[32]; int mraw;
  LOAD_RECS32(jrow, cptr, rc, mraw);
  const int m = valid ? min(mraw, CAP) : 0;
  const unsigned Lraw = ((const unsigned*)(ULA + (size_t)ic * 576 + 512))[pl];
  float accLo = 0.0f, accHi = 0.0f;
  unsigned r[32];
#define CV_OFF(V) (((((unsigned)(V)) >> 6) & 0xFFFFFF80u) + lane4)
#define CV_FMA(V, RD)                                                       \
  {                                                                         \
    float w0_ = dec_w0(V);                                                  \
    float wv_ = half ? (dec_sf(V) - w0_) : w0_;                             \
    accLo = fmaf(wv_, __uint_as_float((RD) << 16), accLo);                  \
    accHi = fmaf(wv_, __uint_as_float((RD) & 0xFFFF0000u), accHi);          \
  }
  if (m > 0) {
    if (m <= 16) {
      #pragma unroll
      for (int k = 0; k < 16; ++k) r[k] = CV_OFF(rc[k]);
      GATHER16(r, ULA);
      #pragma unroll
      for (int k = 0; k < 16; ++k) CV_FMA(rc[k], r[k]);
    } else {
      #pragma unroll
      for (int k = 0; k < 32; ++k) r[k] = CV_OFF(rc[k]);
      GATHER32(r, ULA);
      #pragma unroll
      for (int k = 0; k < 32; ++k) CV_FMA(rc[k], r[k]);
      if (m > 32) {
        int rt[16];
        LOAD_RECS16T(jrow, rt);
        #pragma unroll
        for (int k = 0; k < 16; ++k) r[k] = CV_OFF(rt[k]);
        GATHER16(r, ULA);
        #pragma unroll
        for (int k = 0; k < 16; ++k) CV_FMA(rt[k], r[k]);
      }
    }
  }
  accLo += __shfl_xor(accLo, 32, 64);       // merge u0/u1 halves
  accHi += __shfl_xor(accHi, 32, 64);
  if (half == 0) {                          // lanes 0-31: epilogue
    unsigned* row = (unsigned*)(sXa + w * 64);
    if (valid) {
      const int c0i = 2 * pl, c1i = c0i + 1;
      float o0 = accLo + __uint_as_float(Lraw << 16) + cb[c0i] + fb[c0i];
      float o1 = accHi + __uint_as_float(Lraw & 0xFFFF0000u) + cb[c1i] + fb[c1i];
      *(float2*)(outAns + (size_t)i * 64 + c0i) = make_float2(o0, o1);
      row[pl] = pack2(fmaxf(o0, 0.0f), fmaxf(o1, 0.0f));
    } else {
      row[pl] = 0u;
    }
  }
  __syncthreads();

  gemm_tail(sXa, sUL, WTul2, w, lane);
  __syncthreads();
  const int r2 = tid >> 6;
  const int c0 = tid & 63;
  if (nodeBase + r2 < n) {
    unsigned short* dst = ULB + (size_t)(nodeBase + r2) * 576;
    #pragma unroll
    for (int chunk = c0; chunk < 72; chunk += 64)
      *(short8*)(dst + chunk * 8) = *(const short8*)(sUL + r2 * 584 + chunk * 8);
  }
}

// ---------- conv2: wave per node; gather + resid + fused T ----------
__global__ __launch_bounds__(256, 4) void conv2_kernel(
    const unsigned short* __restrict__ UL,  // ULB [n,576] bf16
    const int* __restrict__ cnt, const int* __restrict__ jw,
    const float* __restrict__ cb, const float* __restrict__ fb,
    const float* __restrict__ resid,        // ans1 fp32 [n,64]
    const float* __restrict__ cW3,          // [8,64,2]
    float* __restrict__ T,                  // [n,18] fp32 (slot p at offset p*2)
    unsigned short* __restrict__ outAnsc, int n) {  // ansc2 bf16 [n,64]
  const int lane = threadIdx.x & 63;
  const int half = lane >> 5;
  const int pl = lane & 31;
  const unsigned lane4 = (unsigned)lane * 4u;
  const int i = (blockIdx.x * blockDim.x + threadIdx.x) >> 6;
  if (i >= n) return;
  const int* jrow = (const int*)rfl64((unsigned long long)(jw + (size_t)i * CAP));
  const int* cptr = (const int*)rfl64((unsigned long long)(cnt + i));
  int rc[32]; int mraw;
  LOAD_RECS32(jrow, cptr, rc, mraw);
  const int m = min(mraw, CAP);
  const unsigned Lraw = ((const unsigned*)(UL + (size_t)i * 576 + 512))[pl];
  float2 rv = *(const float2*)(resid + (size_t)i * 64 + 2 * pl);
  float accLo = 0.0f, accHi = 0.0f;
  unsigned r[32];
  if (m > 0) {
    if (m <= 16) {
      #pragma unroll
      for (int k = 0; k < 16; ++k) r[k] = CV_OFF(rc[k]);
      GATHER16(r, UL);
      #pragma unroll
      for (int k = 0; k < 16; ++k) CV_FMA(rc[k], r[k]);
    } else {
      #pragma unroll
      for (int k = 0; k < 32; ++k) r[k] = CV_OFF(rc[k]);
      GATHER32(r, UL);
      #pragma unroll
      for (int k = 0; k < 32; ++k) CV_FMA(rc[k], r[k]);
      if (m > 32) {
        int rt[16];
        LOAD_RECS16T(jrow, rt);
        #pragma unroll
        for (int k = 0; k < 16; ++k) r[k] = CV_OFF(rt[k]);
        GATHER16(r, UL);
        #pragma unroll
        for (int k = 0; k < 16; ++k) CV_FMA(rt[k], r[k]);
      }
    }
  }
  accLo += __shfl_xor(accLo, 32, 64);
  accHi += __shfl_xor(accHi, 32, 64);
  if (half == 0) {
    const int c0i = 2 * pl, c1i = c0i + 1;
    float o0 = accLo + __uint_as_float(Lraw << 16) + cb[c0i] + fb[c0i] + rv.x;
    float o1 = accHi + __uint_as_float(Lraw & 0xFFFF0000u) + cb[c1i] + fb[c1i] + rv.y;
    unsigned short xb0 = (unsigned short)bf16s(fmaxf(o0, 0.0f));
    unsigned short xb1 = (unsigned short)bf16s(fmaxf(o1, 0.0f));
    ((unsigned*)(outAnsc + (size_t)i * 64))[pl] = (unsigned)xb0 | ((unsigned)xb1 << 16);
    // fused T: T[i][t] = sum_ch ansc2[i,ch] * cW3[t>>1][ch][t&1]
    float x0 = b2f(xb0), x1 = b2f(xb1);
    float c[16];
    #pragma unroll
    for (int t = 0; t < 16; ++t) {
      const float* wrow = cW3 + ((size_t)(t >> 1) * 64) * 2 + (t & 1);
      c[t] = x0 * wrow[c0i * 2] + x1 * wrow[c1i * 2];
    }
    #pragma unroll
    for (int off = 16; off > 0; off >>= 1) {
      #pragma unroll
      for (int t = 0; t < 16; ++t) c[t] += __shfl_xor(c[t], off, 64);
    }
    if (pl == 0) {
      float* tr = T + (size_t)i * 18;     // row stride 18: slot p lives at p*2
      #pragma unroll
      for (int t = 0; t < 16; ++t) tr[t] = c[t];
    }
  }
}

// ---------- layer 3: wave per node, lane = edge; 16B/edge from T; + lin; reduce ----------
__global__ __launch_bounds__(256, 4) void layer3_kernel(
    const unsigned short* __restrict__ Xb,  // ansc2 [n,64] bf16
    const float* __restrict__ T,            // [n,18] fp32
    const int* __restrict__ cnt, const int* __restrict__ jw,
    const float* __restrict__ cb3, const float* __restrict__ fb3,
    const float* __restrict__ fW3,          // [64,2]
    float* __restrict__ out, int n) {
  const int lane = threadIdx.x & 63;
  const int i = (blockIdx.x * blockDim.x + threadIdx.x) >> 6;
  if (i >= n) return;
  const int m = min(cnt[i], CAP);
  float c0 = 0.0f, c1 = 0.0f;
  if (lane < m) {                      // lane = edge index (real records only)
    int v = jw[(size_t)i * CAP + lane];
    unsigned off = (unsigned)v >> 13;  // = j*9 + p; T row = 18 floats = 9 x 8B slots
    float w0 = dec_w0(v);
    float w1 = 1.0f - w0;
    const float* tb = T + (size_t)off * 2;
    float2 ta = *(const float2*)(tb);
    float2 tc = *(const float2*)(tb + 2);
    c0 = w0 * ta.x + w1 * tc.x;
    c1 = w0 * ta.y + w1 * tc.y;
  }
  float xi = b2f(Xb[(size_t)i * 64 + lane]);
  float2 fw = *(const float2*)(fW3 + lane * 2);
  c0 = fmaf(xi, fw.x, c0);
  c1 = fmaf(xi, fw.y, c1);
  #pragma unroll
  for (int off = 32; off > 0; off >>= 1) {
    c0 += __shfl_xor(c0, off, 64);
    c1 += __shfl_xor(c1, off, 64);
  }
  if (lane == 0) {
    out[(size_t)i * 2 + 0] = c0 + cb3[0] + fb3[0];
    out[(size_t)i * 2 + 1] = c1 + cb3[1] + fb3[1];
  }
}

extern "C" void kernel_launch(void* const* d_in, const int* in_sizes, int n_in,
                              void* d_out, int out_size, void* d_ws, size_t ws_size,
                              hipStream_t stream) {
  const float* X    = (const float*)d_in[0];
  const int*   fi   = (const int*)d_in[1];
  const int*   fj   = (const int*)d_in[2];
  const float* dist = (const float*)d_in[3];
  const float* cW0 = (const float*)d_in[4];  const float* cb0 = (const float*)d_in[5];
  const float* fW0 = (const float*)d_in[6];  const float* fb0 = (const float*)d_in[7];
  const float* cW1 = (const float*)d_in[8];  const float* cb1 = (const float*)d_in[9];
  const float* fW1 = (const float*)d_in[10]; const float* fb1 = (const float*)d_in[11];
  const float* cW2 = (const float*)d_in[12]; const float* cb2 = (const float*)d_in[13];
  const float* fW2 = (const float*)d_in[14]; const float* fb2 = (const float*)d_in[15];
  const float* cW3 = (const float*)d_in[16]; const float* cb3 = (const float*)d_in[17];
  const float* fW3 = (const float*)d_in[18]; const float* fb3 = (const float*)d_in[19];
  float* out = (float*)d_out;

  const int n  = in_sizes[0] / 4;  // N = 30000
  const int nE = in_sizes[1];      // E = 480000

  // workspace (~88.9 MB):
  //   ULA bf16[n*576] | ULB bf16[n*576] (U0[n*288] aliases its start; dead after layer0)
  // | ans1 fp32[n*64] | ansc2 bf16[n*64] | T fp32[n*18] | wt1 | wt2 | jw[n*CAP] | cnt[n]
  unsigned short* ULA   = (unsigned short*)d_ws;
  unsigned short* ULB   = ULA + (size_t)n * 576;
  unsigned short* U0    = ULB;                      // alias (dead after layer0_gemm)
  float*          ans1  = (float*)(ULB + (size_t)n * 576);
  unsigned short* ansc2 = (unsigned short*)(ans1 + (size_t)n * 64);
  float* T     = (float*)(ansc2 + (size_t)n * 64);
  short* wtul1 = (short*)(T + (size_t)n * 18);
  short* wtul2 = wtul1 + 576 * 64;
  int*   jw    = (int*)(wtul2 + 576 * 64);
  int*   cnt   = jw + (size_t)n * CAP;

  // zero jw (pad records) AND cnt in one contiguous memset
  hipMemsetAsync(jw, 0, ((size_t)n * CAP + n) * sizeof(int), stream);
  const int fillBlocks = (nE + 255) / 256;
  const int prepBlocks = (2 * 576 * 64 + 255) / 256;
  const int u0Blocks   = (n * 72 + 255) / 256;
  fill_prep<<<fillBlocks + prepBlocks + u0Blocks, 256, 0, stream>>>(
      dist, fi, fj, cnt, jw, nE, cW1, fW1, cW2, fW2, wtul1, wtul2,
      X, cW0, fW0, U0, n, fillBlocks, prepBlocks);

  // layer 0 + gemm_ul1 (reads U0=ULB region, writes ULA)
  layer0_gemm<<<(n + 15) / 16, 1024, 0, stream>>>(U0, cnt, jw, cb0, fb0,
                                                  wtul1, ULA, n);
  // conv1 + gemm_ul2 (reads ULA, writes ans1 + ULB)
  conv_gemm<<<(n + 15) / 16, 1024, 0, stream>>>(ULA, cnt, jw, cb1, fb1,
                                                wtul2, ans1, ULB, n);
  // conv2 (+resid +fused T) (reads ULB, ans1; writes ansc2, T)
  conv2_kernel<<<(n * 64 + 255) / 256, 256, 0, stream>>>(
      ULB, cnt, jw, cb2, fb2, ans1, cW3, T, ansc2, n);
  // layer 3
  layer3_kernel<<<(n * 64 + 255) / 256, 256, 0, stream>>>(ansc2, T, cnt, jw,
                                                          cb3, fb3, fW3, out, n);
}

// Round 6
// 267.967 us; speedup vs baseline: 1.0886x; 1.0886x over previous
//
#include <hip/hip_runtime.h>

// RbfNet on MI355X — round 26:
// R24/R25: forced-residency asm batches -> LLVM demoted the tied-operand
// arrays to scratch (245MB spill writes = exactly 128B/thread), regardless
// of launch_bounds. Register-file batching is a dead end with this compiler.
// NEW: gathers staged through LDS via __builtin_amdgcn_global_load_lds —
// per-lane global src addr, wave-uniform LDS dest + lane*4, ZERO result
// VGPRs, batching inherent (16 slots in flight, one s_waitcnt vmcnt(0)).
// Consume via conflict-free ds_read (slot*256 + lane*4 -> 2 lanes/bank, free).
// Records stay in SGPR v4i quads (proven s_load asm) + constant-fold extract.
// 512-thr blocks (8 waves = 8 nodes); gather region 32KB aliases sUL (dead
// until post-gather barrier); sXa rows 8-15 zeroed for the 16-row MFMA tail.
// LDS 35KB -> 4 blocks/CU, 32 waves/CU @ VGPR<=64.
// Record (4B): off=j*9+p (19b) | real-bit (1b) | wq (12b); w0 = wq*2^-12
// mantissa trick; pads (v=0) decode to w0=w1=0.

#define CAP 48

typedef __attribute__((ext_vector_type(8))) short short8;
typedef __attribute__((ext_vector_type(4))) short short4v;
typedef __attribute__((ext_vector_type(4))) float f32x4;
typedef int v4i __attribute__((ext_vector_type(4)));

__device__ __forceinline__ short bf16s(float f) {   // fp32 -> bf16 RNE
  unsigned u = __float_as_uint(f);
  return (short)((u + 0x7FFF + ((u >> 16) & 1)) >> 16);
}
__device__ __forceinline__ float b2f(unsigned short s) {
  return __uint_as_float(((unsigned)s) << 16);
}
__device__ __forceinline__ unsigned pack2(float a, float b) {
  return (unsigned)(unsigned short)bf16s(a) | ((unsigned)(unsigned short)bf16s(b) << 16);
}
__device__ __forceinline__ float dec_w0(int v) {    // w0 = wq * 2^-12, pad -> 0
  return __uint_as_float(0x3F800000u | (((unsigned)v & 0xFFFu) << 11)) - 1.0f;
}
__device__ __forceinline__ float dec_sf(int v) {    // 1.0 real record, 0.0 pad
  return (float)(((unsigned)v >> 12) & 1u);
}
__device__ __forceinline__ unsigned long long rfl64(unsigned long long x) {
  unsigned lo = __builtin_amdgcn_readfirstlane((unsigned)x);
  unsigned hi = __builtin_amdgcn_readfirstlane((unsigned)(x >> 32));
  return ((unsigned long long)hi << 32) | (unsigned long long)lo;
}
// async global->LDS: per-lane global addr, LDS dest = uniform base + lane*4
__device__ __forceinline__ void gload_lds4(const void* g, void* l) {
  __builtin_amdgcn_global_load_lds(
      (const __attribute__((address_space(1))) void*)g,
      (__attribute__((address_space(3))) void*)l, 4, 0, 0);
}

#define WAIT_VM0 asm volatile("s_waitcnt vmcnt(0)" ::: "memory")
#define WAIT_LGKM0 asm volatile("s_waitcnt lgkmcnt(0)" ::: "memory")

// ---- record fetch: declares q0..q7 + MRAW in scope (SGPRs, wait inside) ----
#define LOAD_RECS32Q(JROW, CPTR, MRAW)                                      \
  v4i q0, q1, q2, q3, q4, q5, q6, q7;                                       \
  int MRAW;                                                                 \
  asm volatile("s_load_dwordx4 %0, %9, 0x0\n\t"                             \
               "s_load_dwordx4 %1, %9, 0x10\n\t"                            \
               "s_load_dwordx4 %2, %9, 0x20\n\t"                            \
               "s_load_dwordx4 %3, %9, 0x30\n\t"                            \
               "s_load_dwordx4 %4, %9, 0x40\n\t"                            \
               "s_load_dwordx4 %5, %9, 0x50\n\t"                            \
               "s_load_dwordx4 %6, %9, 0x60\n\t"                            \
               "s_load_dwordx4 %7, %9, 0x70\n\t"                            \
               "s_load_dword %8, %10, 0x0\n\t"                              \
               "s_waitcnt lgkmcnt(0)"                                       \
               : "=&s"(q0), "=&s"(q1), "=&s"(q2), "=&s"(q3), "=&s"(q4),     \
                 "=&s"(q5), "=&s"(q6), "=&s"(q7), "=&s"(MRAW)               \
               : "s"(JROW), "s"(CPTR)                                       \
               : "memory")

#define LOAD_RECS16TQ(JROW)                                                 \
  v4i qt0, qt1, qt2, qt3;                                                   \
  asm volatile("s_load_dwordx4 %0, %4, 0x80\n\t"                            \
               "s_load_dwordx4 %1, %4, 0x90\n\t"                            \
               "s_load_dwordx4 %2, %4, 0xA0\n\t"                            \
               "s_load_dwordx4 %3, %4, 0xB0\n\t"                            \
               "s_waitcnt lgkmcnt(0)"                                       \
               : "=&s"(qt0), "=&s"(qt1), "=&s"(qt2), "=&s"(qt3)             \
               : "s"(JROW)                                                  \
               : "memory")

// constant-folded record extract (post-unroll K is a literal)
#define RECK(K) ((K) < 4 ? q0[(K) & 3] : (K) < 8 ? q1[(K) & 3] :            \
                 (K) < 12 ? q2[(K) & 3] : (K) < 16 ? q3[(K) & 3] :          \
                 (K) < 20 ? q4[(K) & 3] : (K) < 24 ? q5[(K) & 3] :          \
                 (K) < 28 ? q6[(K) & 3] : q7[(K) & 3])
#define RECT(K) ((K) < 4 ? qt0[(K) & 3] : (K) < 8 ? qt1[(K) & 3] :          \
                 (K) < 12 ? qt2[(K) & 3] : qt3[(K) & 3])

// ---------- fused: edge-bucket build | WTul prep | U0L0 prep (3 block ranges) ----------
__global__ void fill_prep(const float* __restrict__ dist,
                          const int* __restrict__ fi, const int* __restrict__ fj,
                          int* __restrict__ cnt, int* __restrict__ jw, int nE,
                          const float* __restrict__ cW1, const float* __restrict__ fW1,
                          const float* __restrict__ cW2, const float* __restrict__ fW2,
                          short* __restrict__ wt1, short* __restrict__ wt2,
                          const float* __restrict__ X,    // [n,4]
                          const float* __restrict__ cW0,  // [8,4,32]
                          const float* __restrict__ fW0,  // [4,32]
                          unsigned short* __restrict__ U0, int n,
                          int fillBlocks, int prepBlocks) {
  if ((int)blockIdx.x < fillBlocks) {
    int e = blockIdx.x * blockDim.x + threadIdx.x;
    if (e >= nE) return;
    int i = fi[e], j = fj[e];
    if (i == j) return;                  // centerIgnore
    float d = fminf(1.0f, fmaxf(-1.0f, dist[e]));
    float u = (d + 1.0f) * 3.5f;         // hat centers: spacing 2/7
    int p = min((int)u, 6);
    float w0 = 1.0f - (u - (float)p);
    int wq = min((int)(w0 * 4096.0f + 0.5f), 4095);
    unsigned off = (unsigned)(j * 9 + p);          // fused table offset
    int pos = atomicAdd(&cnt[i], 1);
    if (pos < CAP)
      jw[(size_t)i * CAP + pos] = (int)((off << 13) | 0x1000u | (unsigned)wq);
  } else if ((int)blockIdx.x < fillBlocks + prepBlocks) {
    int idx = ((int)blockIdx.x - fillBlocks) * blockDim.x + threadIdx.x;
    if (idx >= 2 * 576 * 64) return;
    int sel = idx / (576 * 64);
    int r = idx - sel * (576 * 64);
    int col = r >> 6, ch = r & 63;
    const float* cW = sel ? cW2 : cW1;
    const float* fW = sel ? fW2 : fW1;
    float v;
    if (col < 512) {
      int p = col >> 6, co = col & 63;
      v = cW[((size_t)p * 64 + ch) * 64 + co];
    } else {
      v = fW[(size_t)ch * 64 + (col - 512)];
    }
    (sel ? wt2 : wt1)[(size_t)col * 64 + ch] = bf16s(v);
  } else {
    // U0L0: [n,288] bf16, 4 channels/thread (groups of 4 never cross a p boundary)
    int idx = ((int)blockIdx.x - fillBlocks - prepBlocks) * blockDim.x + threadIdx.x;
    if (idx >= n * 72) return;
    int i = idx / 72, g = idx - i * 72;
    float4 x = *(const float4*)(X + (size_t)i * 4);
    float xk[4] = {x.x, x.y, x.z, x.w};
    float s[4] = {0, 0, 0, 0};
    if (g < 64) {                        // conv: p = g>>3, channels (g*4)&31 ..+3
      int p = g >> 3;
      int co = (g * 4) & 31;
      #pragma unroll
      for (int k = 0; k < 4; ++k) {
        const float* wr = cW0 + ((size_t)p * 4 + k) * 32 + co;
        #pragma unroll
        for (int c = 0; c < 4; ++c) s[c] = fmaf(xk[k], wr[c], s[c]);
      }
    } else {                             // lin: channels (g-64)*4 ..+3
      int co = (g - 64) * 4;
      #pragma unroll
      for (int k = 0; k < 4; ++k) {
        const float* wr = fW0 + (size_t)k * 32 + co;
        #pragma unroll
        for (int c = 0; c < 4; ++c) s[c] = fmaf(xk[k], wr[c], s[c]);
      }
    }
    uint2 pk = make_uint2(pack2(s[0], s[1]), pack2(s[2], s[3]));
    *(uint2*)(U0 + (size_t)i * 288 + g * 4) = pk;
  }
}

// ---- MFMA tail (8-wave blocks): UL[16,576] = sXa[16,64] @ WT^T (rows 8-15 zero)
__device__ __forceinline__ void gemm_tail8(const unsigned short* sXa, short* sUL,
                                           const short* __restrict__ WT,
                                           int w, int lane) {
  const int mrow = lane & 15;
  const int quad = lane >> 4;
  short8 b0 = *(const short8*)(sXa + mrow * 64 + quad * 8);
  short8 b1 = *(const short8*)(sXa + mrow * 64 + quad * 8 + 32);
  for (int t = w; t < 36; t += 8) {      // 4-5 tiles per wave, low VGPR
    const short* A = WT + (size_t)(t * 16 + mrow) * 64 + quad * 8;
    short8 a0 = *(const short8*)(A);
    short8 a1 = *(const short8*)(A + 32);
    f32x4 acc = {0, 0, 0, 0};
    acc = __builtin_amdgcn_mfma_f32_16x16x32_bf16(a0, b0, acc, 0, 0, 0);
    acc = __builtin_amdgcn_mfma_f32_16x16x32_bf16(a1, b1, acc, 0, 0, 0);
    short4v pk;
    #pragma unroll
    for (int r = 0; r < 4; ++r) pk[r] = bf16s(acc[r]);
    *(short4v*)(sUL + mrow * 584 + t * 16 + quad * 4) = pk;
  }
}

// ---------- FUSED layer0 + gemm_ul1: 512 threads, 8 waves = 8 nodes ----------
__global__ __launch_bounds__(512, 8) void layer0_gemm(
    const unsigned short* __restrict__ U0,  // [n,288] bf16 (p-major conv ++ lin)
    const int* __restrict__ cnt, const int* __restrict__ jw,
    const float* __restrict__ cb0, const float* __restrict__ fb0,
    const short* __restrict__ WTul,   // [576,64] bf16 layer-1 weights
    unsigned short* __restrict__ UL, int n) {
  __shared__ __align__(16) char smem[8 * 4096];           // gather; aliased by sUL
  __shared__ __align__(16) unsigned short sXa[16 * 64];   // ansc0 tile (rows 8-15 = 0)
  const int tid = threadIdx.x;
  const int w = tid >> 6;                 // wave 0..7, owns node w
  const int lane = tid & 63;
  const int grp = lane >> 5;              // 0: even edges, 1: odd edges
  const int gl = lane & 31;
  const unsigned gl4 = (unsigned)gl * 4u;
  const int nodeBase = blockIdx.x * 8;
  const int i = nodeBase + w;
  const bool valid = (i < n);
  const int ic = valid ? i : 0;
  if (tid < 256) ((unsigned*)sXa)[256 + tid] = 0u;   // zero MFMA rows 8..15
  const int* jrow = (const int*)rfl64((unsigned long long)(jw + (size_t)ic * CAP));
  const int* cptr = (const int*)rfl64((unsigned long long)(cnt + ic));
  LOAD_RECS32Q(jrow, cptr, mraw);
  const int m = valid ? min(mraw, CAP) : 0;
  char* ldsW = smem + w * 4096;
  unsigned* ldsWu = (unsigned*)ldsW;
  const char* u0B = (const char*)U0;
  float accLo = 0.0f, accHi = 0.0f;
  // slot K covers edges 2K (lanes 0-31) and 2K+1 (lanes 32-63); 4B/lane
#define L0_ISSUE(K, RE)                                                     \
  { int v_ = grp ? RE(2 * (K) + 1) : RE(2 * (K));                           \
    unsigned soff_ = (((unsigned)v_) >> 7) & 0xFFFFFFC0u;                   \
    gload_lds4(u0B + soff_ + gl4, ldsW + (K) * 256); }
#define L0_CONS(K, RE)                                                      \
  { int v_ = grp ? RE(2 * (K) + 1) : RE(2 * (K));                           \
    float w0_ = dec_w0(v_);                                                 \
    float wgt_ = (gl < 16) ? w0_ : (dec_sf(v_) - w0_);                      \
    unsigned rd_ = ldsWu[(K) * 64 + lane];                                  \
    accLo = fmaf(wgt_, __uint_as_float(rd_ << 16), accLo);                  \
    accHi = fmaf(wgt_, __uint_as_float(rd_ & 0xFFFF0000u), accHi); }
  if (m > 0) {
    if (m <= 16) {                        // 8 slots (pads decode to weight 0)
      #pragma unroll
      for (int k = 0; k < 8; ++k) L0_ISSUE(k, RECK);
      WAIT_VM0;
      #pragma unroll
      for (int k = 0; k < 8; ++k) L0_CONS(k, RECK);
    } else {
      #pragma unroll
      for (int k = 0; k < 16; ++k) L0_ISSUE(k, RECK);
      WAIT_VM0;
      #pragma unroll
      for (int k = 0; k < 16; ++k) L0_CONS(k, RECK);
      if (m > 32) {                       // rare tail, reuse slots 0..7
        LOAD_RECS16TQ(jrow);
        WAIT_LGKM0;
        #pragma unroll
        for (int k = 0; k < 8; ++k) L0_ISSUE(k, RECT);
        WAIT_VM0;
        #pragma unroll
        for (int k = 0; k < 8; ++k) L0_CONS(k, RECT);
      }
    }
  }
#undef L0_ISSUE
#undef L0_CONS
  accLo += __shfl_xor(accLo, 16, 64);     // merge w0/w1 slice roles
  accHi += __shfl_xor(accHi, 16, 64);
  accLo += __shfl_xor(accLo, 32, 64);     // merge even/odd edge groups
  accHi += __shfl_xor(accHi, 32, 64);
  if (lane < 16) {                        // lane l holds conv ch-pair (2l, 2l+1)
    const int l = lane;
    float c0v = fmaxf(accLo + cb0[2 * l], 0.0f);
    float c1v = fmaxf(accHi + cb0[2 * l + 1], 0.0f);
    unsigned lr = ((const unsigned*)(U0 + (size_t)ic * 288 + 256))[l];
    float l0 = fmaxf(__uint_as_float(lr << 16) + fb0[2 * l], 0.0f);
    float l1 = fmaxf(__uint_as_float(lr & 0xFFFF0000u) + fb0[2 * l + 1], 0.0f);
    unsigned* row = (unsigned*)(sXa + w * 64);
    row[l] = pack2(l0, l1);
    row[16 + l] = pack2(c0v, c1v);
  }
  __syncthreads();                        // gather region dead; sUL may alias

  gemm_tail8(sXa, (short*)smem, WTul, w, lane);
  __syncthreads();
  const int r2 = tid >> 6;                // 0..7
  const int c0 = tid & 63;
  if (nodeBase + r2 < n) {
    const short* sUL = (const short*)smem;
    unsigned short* dst = UL + (size_t)(nodeBase + r2) * 576;
    #pragma unroll
    for (int chunk = c0; chunk < 72; chunk += 64)
      *(short8*)(dst + chunk * 8) = *(const short8*)(sUL + r2 * 584 + chunk * 8);
  }
}

// ---------- FUSED conv1 + gemm_ul2: 512 threads, 8 waves = 8 nodes ----------
__global__ __launch_bounds__(512, 8) void conv_gemm(
    const unsigned short* __restrict__ ULA, // [n,576] bf16 (layer-1 U/L)
    const int* __restrict__ cnt, const int* __restrict__ jw,
    const float* __restrict__ cb, const float* __restrict__ fb,
    const short* __restrict__ WTul2,        // [576,64] bf16 layer-2 weights
    float* __restrict__ outAns,             // ans1 fp32 [n,64] (resid for conv2)
    unsigned short* __restrict__ ULB, int n) {
  __shared__ __align__(16) char smem[8 * 4096];           // gather; aliased by sUL
  __shared__ __align__(16) unsigned short sXa[16 * 64];
  const int tid = threadIdx.x;
  const int w = tid >> 6;
  const int lane = tid & 63;
  const int half = lane >> 5;               // 0 -> u0 (w0), 1 -> u1 (w1)
  const int pl = lane & 31;
  const unsigned lane4 = (unsigned)lane * 4u;
  const int nodeBase = blockIdx.x * 8;
  const int i = nodeBase + w;
  const bool valid = (i < n);
  const int ic = valid ? i : 0;
  if (tid < 256) ((unsigned*)sXa)[256 + tid] = 0u;
  const int* jrow = (const int*)rfl64((unsigned long long)(jw + (size_t)ic * CAP));
  const int* cptr = (const int*)rfl64((unsigned long long)(cnt + ic));
  LOAD_RECS32Q(jrow, cptr, mraw);
  const int m = valid ? min(mraw, CAP) : 0;
  const unsigned Lraw = ((const unsigned*)(ULA + (size_t)ic * 576 + 512))[pl];
  char* ldsW = smem + w * 4096;
  unsigned* ldsWu = (unsigned*)ldsW;
  const char* ulB = (const char*)ULA;
  float accLo = 0.0f, accHi = 0.0f;
#define CV_ISSUE(K, RE)                                                     \
  { unsigned soff_ = (((unsigned)RE(K)) >> 6) & 0xFFFFFF80u;                \
    gload_lds4(ulB + soff_ + lane4, ldsW + ((K) & 15) * 256); }
#define CV_CONS(K, RE)                                                      \
  { int v_ = RE(K);                                                         \
    float w0_ = dec_w0(v_);                                                 \
    float wv_ = half ? (dec_sf(v_) - w0_) : w0_;                            \
    unsigned rd_ = ldsWu[((K) & 15) * 64 + lane];                           \
    accLo = fmaf(wv_, __uint_as_float(rd_ << 16), accLo);                   \
    accHi = fmaf(wv_, __uint_as_float(rd_ & 0xFFFF0000u), accHi); }
  if (m > 0) {
    #pragma unroll
    for (int k = 0; k < 16; ++k) CV_ISSUE(k, RECK);
    WAIT_VM0;
    #pragma unroll
    for (int k = 0; k < 16; ++k) CV_CONS(k, RECK);
    if (m > 16) {
      WAIT_LGKM0;                         // batch-1 ds_reads done before reuse
      #pragma unroll
      for (int k = 16; k < 32; ++k) CV_ISSUE(k, RECK);
      WAIT_VM0;
      #pragma unroll
      for (int k = 16; k < 32; ++k) CV_CONS(k, RECK);
      if (m > 32) {
        LOAD_RECS16TQ(jrow);
        WAIT_LGKM0;
        #pragma unroll
        for (int k = 0; k < 16; ++k) CV_ISSUE(k, RECT);
        WAIT_VM0;
        #pragma unroll
        for (int k = 0; k < 16; ++k) CV_CONS(k, RECT);
      }
    }
  }
#undef CV_ISSUE
#undef CV_CONS
  accLo += __shfl_xor(accLo, 32, 64);       // merge u0/u1 halves
  accHi += __shfl_xor(accHi, 32, 64);
  if (half == 0) {                          // lanes 0-31: epilogue
    unsigned* row = (unsigned*)(sXa + w * 64);
    if (valid) {
      const int c0i = 2 * pl, c1i = c0i + 1;
      float o0 = accLo + __uint_as_float(Lraw << 16) + cb[c0i] + fb[c0i];
      float o1 = accHi + __uint_as_float(Lraw & 0xFFFF0000u) + cb[c1i] + fb[c1i];
      *(float2*)(outAns + (size_t)i * 64 + c0i) = make_float2(o0, o1);
      row[pl] = pack2(fmaxf(o0, 0.0f), fmaxf(o1, 0.0f));
    } else {
      row[pl] = 0u;
    }
  }
  __syncthreads();

  gemm_tail8(sXa, (short*)smem, WTul2, w, lane);
  __syncthreads();
  const int r2 = tid >> 6;
  const int c0 = tid & 63;
  if (nodeBase + r2 < n) {
    const short* sUL = (const short*)smem;
    unsigned short* dst = ULB + (size_t)(nodeBase + r2) * 576;
    #pragma unroll
    for (int chunk = c0; chunk < 72; chunk += 64)
      *(short8*)(dst + chunk * 8) = *(const short8*)(sUL + r2 * 584 + chunk * 8);
  }
}

// ---------- conv2: 256 threads, 4 waves = 4 nodes; gather + resid + fused T ----------
__global__ __launch_bounds__(256, 8) void conv2_kernel(
    const unsigned short* __restrict__ UL,  // ULB [n,576] bf16
    const int* __restrict__ cnt, const int* __restrict__ jw,
    const float* __restrict__ cb, const float* __restrict__ fb,
    const float* __restrict__ resid,        // ans1 fp32 [n,64]
    const float* __restrict__ cW3,          // [8,64,2]
    float* __restrict__ T,                  // [n,18] fp32 (slot p at offset p*2)
    unsigned short* __restrict__ outAnsc, int n) {  // ansc2 bf16 [n,64]
  __shared__ __align__(16) char smem2[4 * 4096];
  const int lane = threadIdx.x & 63;
  const int half = lane >> 5;
  const int pl = lane & 31;
  const unsigned lane4 = (unsigned)lane * 4u;
  const int w4 = threadIdx.x >> 6;          // 0..3
  const int i = (blockIdx.x * blockDim.x + threadIdx.x) >> 6;
  if (i >= n) return;                       // no barriers in this kernel
  const int* jrow = (const int*)rfl64((unsigned long long)(jw + (size_t)i * CAP));
  const int* cptr = (const int*)rfl64((unsigned long long)(cnt + i));
  LOAD_RECS32Q(jrow, cptr, mraw);
  const int m = min(mraw, CAP);
  const unsigned Lraw = ((const unsigned*)(UL + (size_t)i * 576 + 512))[pl];
  float2 rv = *(const float2*)(resid + (size_t)i * 64 + 2 * pl);
  char* ldsW = smem2 + w4 * 4096;
  unsigned* ldsWu = (unsigned*)ldsW;
  const char* ulB = (const char*)UL;
  float accLo = 0.0f, accHi = 0.0f;
#define CV_ISSUE(K, RE)                                                     \
  { unsigned soff_ = (((unsigned)RE(K)) >> 6) & 0xFFFFFF80u;                \
    gload_lds4(ulB + soff_ + lane4, ldsW + ((K) & 15) * 256); }
#define CV_CONS(K, RE)                                                      \
  { int v_ = RE(K);                                                         \
    float w0_ = dec_w0(v_);                                                 \
    float wv_ = half ? (dec_sf(v_) - w0_) : w0_;                            \
    unsigned rd_ = ldsWu[((K) & 15) * 64 + lane];                           \
    accLo = fmaf(wv_, __uint_as_float(rd_ << 16), accLo);                   \
    accHi = fmaf(wv_, __uint_as_float(rd_ & 0xFFFF0000u), accHi); }
  if (m > 0) {
    #pragma unroll
    for (int k = 0; k < 16; ++k) CV_ISSUE(k, RECK);
    WAIT_VM0;
    #pragma unroll
    for (int k = 0; k < 16; ++k) CV_CONS(k, RECK);
    if (m > 16) {
      WAIT_LGKM0;
      #pragma unroll
      for (int k = 16; k < 32; ++k) CV_ISSUE(k, RECK);
      WAIT_VM0;
      #pragma unroll
      for (int k = 16; k < 32; ++k) CV_CONS(k, RECK);
      if (m > 32) {
        LOAD_RECS16TQ(jrow);
        WAIT_LGKM0;
        #pragma unroll
        for (int k = 0; k < 16; ++k) CV_ISSUE(k, RECT);
        WAIT_VM0;
        #pragma unroll
        for (int k = 0; k < 16; ++k) CV_CONS(k, RECT);
      }
    }
  }
#undef CV_ISSUE
#undef CV_CONS
  accLo += __shfl_xor(accLo, 32, 64);
  accHi += __shfl_xor(accHi, 32, 64);
  if (half == 0) {
    const int c0i = 2 * pl, c1i = c0i + 1;
    float o0 = accLo + __uint_as_float(Lraw << 16) + cb[c0i] + fb[c0i] + rv.x;
    float o1 = accHi + __uint_as_float(Lraw & 0xFFFF0000u) + cb[c1i] + fb[c1i] + rv.y;
    unsigned short xb0 = (unsigned short)bf16s(fmaxf(o0, 0.0f));
    unsigned short xb1 = (unsigned short)bf16s(fmaxf(o1, 0.0f));
    ((unsigned*)(outAnsc + (size_t)i * 64))[pl] = (unsigned)xb0 | ((unsigned)xb1 << 16);
    // fused T: T[i][t] = sum_ch ansc2[i,ch] * cW3[t>>1][ch][t&1]
    float x0 = b2f(xb0), x1 = b2f(xb1);
    float c[16];
    #pragma unroll
    for (int t = 0; t < 16; ++t) {
      const float* wrow = cW3 + ((size_t)(t >> 1) * 64) * 2 + (t & 1);
      c[t] = x0 * wrow[c0i * 2] + x1 * wrow[c1i * 2];
    }
    #pragma unroll
    for (int off = 16; off > 0; off >>= 1) {
      #pragma unroll
      for (int t = 0; t < 16; ++t) c[t] += __shfl_xor(c[t], off, 64);
    }
    if (pl == 0) {
      float* tr = T + (size_t)i * 18;     // row stride 18: slot p lives at p*2
      #pragma unroll
      for (int t = 0; t < 16; ++t) tr[t] = c[t];
    }
  }
}

// ---------- layer 3: wave per node, lane = edge; 16B/edge from T; + lin; reduce ----------
__global__ __launch_bounds__(256, 4) void layer3_kernel(
    const unsigned short* __restrict__ Xb,  // ansc2 [n,64] bf16
    const float* __restrict__ T,            // [n,18] fp32
    const int* __restrict__ cnt, const int* __restrict__ jw,
    const float* __restrict__ cb3, const float* __restrict__ fb3,
    const float* __restrict__ fW3,          // [64,2]
    float* __restrict__ out, int n) {
  const int lane = threadIdx.x & 63;
  const int i = (blockIdx.x * blockDim.x + threadIdx.x) >> 6;
  if (i >= n) return;
  const int m = min(cnt[i], CAP);
  float c0 = 0.0f, c1 = 0.0f;
  if (lane < m) {                      // lane = edge index (real records only)
    int v = jw[(size_t)i * CAP + lane];
    unsigned off = (unsigned)v >> 13;  // = j*9 + p; T row = 18 floats = 9 x 8B slots
    float w0 = dec_w0(v);
    float w1 = 1.0f - w0;
    const float* tb = T + (size_t)off * 2;
    float2 ta = *(const float2*)(tb);
    float2 tc = *(const float2*)(tb + 2);
    c0 = w0 * ta.x + w1 * tc.x;
    c1 = w0 * ta.y + w1 * tc.y;
  }
  float xi = b2f(Xb[(size_t)i * 64 + lane]);
  float2 fw = *(const float2*)(fW3 + lane * 2);
  c0 = fmaf(xi, fw.x, c0);
  c1 = fmaf(xi, fw.y, c1);
  #pragma unroll
  for (int off = 32; off > 0; off >>= 1) {
    c0 += __shfl_xor(c0, off, 64);
    c1 += __shfl_xor(c1, off, 64);
  }
  if (lane == 0) {
    out[(size_t)i * 2 + 0] = c0 + cb3[0] + fb3[0];
    out[(size_t)i * 2 + 1] = c1 + cb3[1] + fb3[1];
  }
}

extern "C" void kernel_launch(void* const* d_in, const int* in_sizes, int n_in,
                              void* d_out, int out_size, void* d_ws, size_t ws_size,
                              hipStream_t stream) {
  const float* X    = (const float*)d_in[0];
  const int*   fi   = (const int*)d_in[1];
  const int*   fj   = (const int*)d_in[2];
  const float* dist = (const float*)d_in[3];
  const float* cW0 = (const float*)d_in[4];  const float* cb0 = (const float*)d_in[5];
  const float* fW0 = (const float*)d_in[6];  const float* fb0 = (const float*)d_in[7];
  const float* cW1 = (const float*)d_in[8];  const float* cb1 = (const float*)d_in[9];
  const float* fW1 = (const float*)d_in[10]; const float* fb1 = (const float*)d_in[11];
  const float* cW2 = (const float*)d_in[12]; const float* cb2 = (const float*)d_in[13];
  const float* fW2 = (const float*)d_in[14]; const float* fb2 = (const float*)d_in[15];
  const float* cW3 = (const float*)d_in[16]; const float* cb3 = (const float*)d_in[17];
  const float* fW3 = (const float*)d_in[18]; const float* fb3 = (const float*)d_in[19];
  float* out = (float*)d_out;

  const int n  = in_sizes[0] / 4;  // N = 30000
  const int nE = in_sizes[1];      // E = 480000

  // workspace (~88.9 MB):
  //   ULA bf16[n*576] | ULB bf16[n*576] (U0[n*288] aliases its start; dead after layer0)
  // | ans1 fp32[n*64] | ansc2 bf16[n*64] | T fp32[n*18] | wt1 | wt2 | jw[n*CAP] | cnt[n]
  unsigned short* ULA   = (unsigned short*)d_ws;
  unsigned short* ULB   = ULA + (size_t)n * 576;
  unsigned short* U0    = ULB;                      // alias (dead after layer0_gemm)
  float*          ans1  = (float*)(ULB + (size_t)n * 576);
  unsigned short* ansc2 = (unsigned short*)(ans1 + (size_t)n * 64);
  float* T     = (float*)(ansc2 + (size_t)n * 64);
  short* wtul1 = (short*)(T + (size_t)n * 18);
  short* wtul2 = wtul1 + 576 * 64;
  int*   jw    = (int*)(wtul2 + 576 * 64);
  int*   cnt   = jw + (size_t)n * CAP;

  // zero jw (pad records) AND cnt in one contiguous memset
  hipMemsetAsync(jw, 0, ((size_t)n * CAP + n) * sizeof(int), stream);
  const int fillBlocks = (nE + 255) / 256;
  const int prepBlocks = (2 * 576 * 64 + 255) / 256;
  const int u0Blocks   = (n * 72 + 255) / 256;
  fill_prep<<<fillBlocks + prepBlocks + u0Blocks, 256, 0, stream>>>(
      dist, fi, fj, cnt, jw, nE, cW1, fW1, cW2, fW2, wtul1, wtul2,
      X, cW0, fW0, U0, n, fillBlocks, prepBlocks);

  // layer 0 + gemm_ul1 (reads U0=ULB region, writes ULA)
  layer0_gemm<<<(n + 7) / 8, 512, 0, stream>>>(U0, cnt, jw, cb0, fb0,
                                               wtul1, ULA, n);
  // conv1 + gemm_ul2 (reads ULA, writes ans1 + ULB)
  conv_gemm<<<(n + 7) / 8, 512, 0, stream>>>(ULA, cnt, jw, cb1, fb1,
                                             wtul2, ans1, ULB, n);
  // conv2 (+resid +fused T) (reads ULB, ans1; writes ansc2, T)
  conv2_kernel<<<(n * 64 + 255) / 256, 256, 0, stream>>>(
      ULB, cnt, jw, cb2, fb2, ans1, cW3, T, ansc2, n);
  // layer 3
  layer3_kernel<<<(n * 64 + 255) / 256, 256, 0, stream>>>(ansc2, T, cnt, jw,
                                                          cb3, fb3, fW3, out, n);
}